// Round 12
// baseline (29.858 us; speedup 1.0000x reference)
//
#include <hip/hip_runtime.h>
#include <math.h>

#define MAP_SIZE 256
#define KV 64
#define HPX (1.0f / 256.0f)
#define TK 288539.0083f            // 2 * 100000 * log2(e)

struct Chain {
    float ax, ay, u;       // carried A-m and sign(ay)
    float mindd, wn2;
    float macr, scr, sdt;  // argmin-|cr| state
};

__device__ __forceinline__ void chainInit(Chain& c, float vx, float vy,
                                          float mx, float my) {
    c.ax = vx - mx; c.ay = vy - my;
    c.u  = __builtin_copysignf(1.0f, c.ay);
    c.mindd = 1e30f; c.wn2 = 0.0f;
    c.macr = 1e30f; c.scr = 1.0f; c.sdt = 1.0f;
}

__device__ __forceinline__ void edgeStep(Chain& s, float bx, float by,
                                         float mx, float my) {
    const float rx = bx - mx;
    const float ry = by - my;
    const float rr = fmaf(rx, rx, ry * ry);
    s.mindd = fminf(s.mindd, rr);
    const float cr = fmaf(s.ay, rx, -s.ax * ry);
    const float dt = fmaf(s.ax, rx, s.ay * ry);
    const float un = __builtin_copysignf(1.0f, ry);
    const float c  = __builtin_copysignf(1.0f, cr);
    const float dl = (un - s.u) * 0.5f;
    s.wn2 = fmaf(dl * fmaf(-c, dl, 1.0f), 0.5f, s.wn2);
    const float acr = __builtin_fabsf(cr);
    const bool better = acr < s.macr;
    s.macr = fminf(acr, s.macr);
    s.scr  = better ? cr : s.scr;
    s.sdt  = better ? dt : s.sdt;
    s.ax = rx; s.ay = ry; s.u = un;
}

__global__ __launch_bounds__(256) void cdm_pass1(
    const float* __restrict__ contour,   // (bn, KV, 2)
    float* __restrict__ out,             // (bn, 256, 256) unnormalized prod
    float* __restrict__ bmax)            // per-block max (no atomics)
{
    __shared__ float4 cv4[KV / 2];       // vertex pairs (2j, 2j+1)
    const int blocksPerImg = (MAP_SIZE * MAP_SIZE) / 256;  // 256
    const int bn  = blockIdx.x / blocksPerImg;
    const int pix = (blockIdx.x % blocksPerImg) * 256 + threadIdx.x;

    if (threadIdx.x < KV / 2)
        cv4[threadIdx.x] = ((const float4*)contour)[bn * (KV / 2) + threadIdx.x];
    __syncthreads();

    const float mx = (float)(pix >> 8) * HPX;
    const float my = (float)(pix & 255) * HPX;

    // TWO independent 32-edge chains (ILP x2): v0..v32 and v32..v64(=v0)
    const float4 q0  = cv4[0];
    const float4 q16 = cv4[16];

    Chain c0, c1;
    chainInit(c0, q0.x,  q0.y,  mx, my);
    chainInit(c1, q16.x, q16.y, mx, my);

    edgeStep(c0, q0.z,  q0.w,  mx, my);   // v0  -> v1
    edgeStep(c1, q16.z, q16.w, mx, my);   // v32 -> v33

    #pragma unroll 3
    for (int jj = 1; jj < 16; ++jj) {
        const float4 t0 = cv4[jj];
        const float4 t1 = cv4[jj + 16];
        edgeStep(c0, t0.x, t0.y, mx, my);  // -> v(2jj)
        edgeStep(c1, t1.x, t1.y, mx, my);  // -> v(2jj+32)
        edgeStep(c0, t0.z, t0.w, mx, my);  // -> v(2jj+1)
        edgeStep(c1, t1.z, t1.w, mx, my);  // -> v(2jj+33)
    }
    edgeStep(c0, q16.x, q16.y, mx, my);   // v31 -> v32
    edgeStep(c1, q0.x,  q0.y,  mx, my);   // v63 -> v0

    // merge the two chains
    const float mindd = fminf(c0.mindd, c1.mindd);
    const float wn2   = c0.wn2 + c1.wn2;
    const bool  b1    = c1.macr < c0.macr;
    const float macr  = fminf(c0.macr, c1.macr);
    const float scr   = b1 ? c1.scr : c0.scr;
    const float sdt   = b1 ? c1.sdt : c0.sdt;

    // epilogue: single trans evaluation for the dominant deviation term
    const float e    = __builtin_amdgcn_exp2f(macr * TK);
    const float d2   = __builtin_amdgcn_rcpf(e + 1.0f);
    const float w    = fmaf(-0.5f, __builtin_copysignf(1.0f, sdt), 0.5f); // [dot<0]
    const float corr = __builtin_copysignf(1.0f, scr) * d2 * w;

    const float resize = __builtin_fabsf(wn2 + corr);
    const float pv = resize * __builtin_amdgcn_sqrtf(mindd);
    out[bn * (MAP_SIZE * MAP_SIZE) + pix] = pv;

    // block max -> plain store (no global atomic)
    float m = pv;
    #pragma unroll
    for (int off = 32; off > 0; off >>= 1)
        m = fmaxf(m, __shfl_xor(m, off));

    __shared__ float wmax[4];
    const int lane = threadIdx.x & 63;
    const int wid  = threadIdx.x >> 6;
    if (lane == 0) wmax[wid] = m;
    __syncthreads();
    if (threadIdx.x == 0)
        bmax[blockIdx.x] = fmaxf(fmaxf(wmax[0], wmax[1]), fmaxf(wmax[2], wmax[3]));
}

__global__ __launch_bounds__(256) void cdm_pass2(
    float4* __restrict__ out, const float* __restrict__ bmax, int nb, int n4)
{
    // every block re-reduces the block-max array (8 KB, L2-resident)
    float m = 0.0f;
    for (int i = threadIdx.x; i < nb; i += 256) m = fmaxf(m, bmax[i]);
    #pragma unroll
    for (int off = 32; off > 0; off >>= 1)
        m = fmaxf(m, __shfl_xor(m, off));

    __shared__ float wm[4];
    if ((threadIdx.x & 63) == 0) wm[threadIdx.x >> 6] = m;
    __syncthreads();
    const float gm  = fmaxf(fmaxf(wm[0], wm[1]), fmaxf(wm[2], wm[3]));
    const float inv = 1.0f / gm;

    const int i = blockIdx.x * 256 + threadIdx.x;
    if (i < n4) {
        float4 v = out[i];
        v.x *= inv; v.y *= inv; v.z *= inv; v.w *= inv;
        out[i] = v;
    }
}

extern "C" void kernel_launch(void* const* d_in, const int* in_sizes, int n_in,
                              void* d_out, int out_size, void* d_ws, size_t ws_size,
                              hipStream_t stream) {
    const float* contour = (const float*)d_in[0];
    float* out  = (float*)d_out;
    float* bmax = (float*)d_ws;

    const int bn = in_sizes[0] / (KV * 2);            // 8
    const int npix = bn * MAP_SIZE * MAP_SIZE;        // 524288 == out_size

    const int blocksPerImg = (MAP_SIZE * MAP_SIZE) / 256;  // 256
    const int nb = bn * blocksPerImg;                       // 2048
    cdm_pass1<<<nb, 256, 0, stream>>>(contour, out, bmax);

    const int n4 = npix / 4;
    cdm_pass2<<<(n4 + 255) / 256, 256, 0, stream>>>((float4*)out, bmax, nb, n4);
}

// Round 13
// 23.750 us; speedup vs baseline: 1.2572x; 1.2572x over previous
//
#include <hip/hip_runtime.h>
#include <math.h>

#define MAP_SIZE 256
#define KV 64
#define PPT 4                      // 4 consecutive-y pixels per thread
#define HPX (1.0f / 256.0f)
#define TK 288539.0083f            // 2 * 100000 * log2(e)

__global__ __launch_bounds__(64) void cdm_pass1(
    const float* __restrict__ contour,   // (bn, KV, 2)
    float* __restrict__ out,             // (bn, 256, 256) unnormalized prod
    float* __restrict__ bmax)            // per-block max (no atomics)
{
    __shared__ __align__(16) float2 cv2[KV + 2];   // [64] = v0 (wrap, no mod)
    const int blocksPerImg = (MAP_SIZE * MAP_SIZE) / (64 * PPT);  // 256
    const int bn = blockIdx.x / blocksPerImg;
    const int p0 = (blockIdx.x % blocksPerImg) * (64 * PPT) + threadIdx.x * PPT;

    const float2* gsrc = (const float2*)contour + bn * KV;
    cv2[threadIdx.x] = gsrc[threadIdx.x];
    if (threadIdx.x == 0) cv2[KV] = gsrc[0];
    __syncthreads();

    const float mx  = (float)(p0 >> 8) * HPX;    // shared by the 4 pixels
    const float my0 = (float)(p0 & 255) * HPX;   // pixel i at my0 + i*HPX

    const float4 q0 = ((const float4*)cv2)[0];   // v0, v1
    float ax  = q0.x - mx;                       // carried A-m (x shared, y px0)
    float ay0 = q0.y - my0;

    float u[PPT], wn2[PPT], mind[PPT], scr[PPT];
    int sidx[PPT];
    #pragma unroll
    for (int i = 0; i < PPT; ++i) {
        u[i] = __builtin_copysignf(1.0f, ay0 - (float)i * HPX);
        wn2[i] = 0.0f; mind[i] = 1e30f; scr[i] = 1.0f; sidx[i] = 0;
    }

    // Slim zero-trans edge step: shared terms once, ~14 VALU per pixel.
    // Argmin tracked as (signed cr, edge index); dot recomputed in epilogue.
    auto edge = [&](float bx, float by, int k) {
        const float rx  = bx - mx;
        const float ry0 = by - my0;
        const float rxx = rx * rx;
        const float ex  = rx - ax;                   // Bx - Ax
        const float cr0 = fmaf(ay0, rx, -ax * ry0);  // cross for px0
        #pragma unroll
        for (int i = 0; i < PPT; ++i) {
            const float iH = (float)i * HPX;
            const float ry = ry0 - iH;
            const float rr = fmaf(ry, ry, rxx);
            mind[i] = fminf(mind[i], rr);
            const float cr = fmaf(-iH, ex, cr0);
            const float un = __builtin_copysignf(1.0f, ry);
            const float c  = __builtin_copysignf(1.0f, cr);
            const float dl = (un - u[i]) * 0.5f;
            wn2[i] = fmaf(dl * fmaf(-c, dl, 1.0f), 0.5f, wn2[i]);
            const bool better = __builtin_fabsf(cr) < __builtin_fabsf(scr[i]);
            scr[i]  = better ? cr : scr[i];          // signed cr of argmin
            sidx[i] = better ? k  : sidx[i];         // its edge index
            u[i] = un;
        }
        ax = rx; ay0 = ry0;
    };

    edge(q0.z, q0.w, 0);                       // edge 0: v0 -> v1
    #pragma unroll 2
    for (int jj = 1; jj < KV / 2; ++jj) {
        const float4 t = ((const float4*)cv2)[jj];
        edge(t.x, t.y, 2 * jj - 1);            // edge 2jj-1: B = v(2jj)
        edge(t.z, t.w, 2 * jj);                // edge 2jj  : B = v(2jj+1)
    }
    edge(q0.x, q0.y, KV - 1);                  // edge 63: v63 -> v0

    // epilogue: one trans evaluation per pixel on the argmin edge
    float pv[PPT];
    #pragma unroll
    for (int i = 0; i < PPT; ++i) {
        const float2 A = cv2[sidx[i]];
        const float2 B = cv2[sidx[i] + 1];
        const float myi = my0 + (float)i * HPX;
        const float dax = A.x - mx, day = A.y - myi;
        const float rbx = B.x - mx, rby = B.y - myi;
        const float dot = fmaf(dax, rbx, day * rby);
        const float e   = __builtin_amdgcn_exp2f(__builtin_fabsf(scr[i]) * TK);
        const float d2  = __builtin_amdgcn_rcpf(e + 1.0f);
        const float w   = fmaf(-0.5f, __builtin_copysignf(1.0f, dot), 0.5f); // [dot<0]
        const float corr = __builtin_copysignf(1.0f, scr[i]) * d2 * w;
        const float resize = __builtin_fabsf(wn2[i] + corr);
        pv[i] = resize * __builtin_amdgcn_sqrtf(mind[i]);
    }

    *(float4*)(out + bn * (MAP_SIZE * MAP_SIZE) + p0) =
        make_float4(pv[0], pv[1], pv[2], pv[3]);

    // 1-wave block: pure shuffle max reduce, no LDS, no extra sync
    float m = fmaxf(fmaxf(pv[0], pv[1]), fmaxf(pv[2], pv[3]));
    #pragma unroll
    for (int off = 32; off > 0; off >>= 1)
        m = fmaxf(m, __shfl_xor(m, off));
    if (threadIdx.x == 0) bmax[blockIdx.x] = m;
}

__global__ __launch_bounds__(256) void cdm_pass2(
    float4* __restrict__ out, const float* __restrict__ bmax, int nb, int n4)
{
    // every block re-reduces the block-max array (8 KB, L2-resident)
    float m = 0.0f;
    for (int i = threadIdx.x; i < nb; i += 256) m = fmaxf(m, bmax[i]);
    #pragma unroll
    for (int off = 32; off > 0; off >>= 1)
        m = fmaxf(m, __shfl_xor(m, off));

    __shared__ float wm[4];
    if ((threadIdx.x & 63) == 0) wm[threadIdx.x >> 6] = m;
    __syncthreads();
    const float gm  = fmaxf(fmaxf(wm[0], wm[1]), fmaxf(wm[2], wm[3]));
    const float inv = 1.0f / gm;

    const int i = blockIdx.x * 256 + threadIdx.x;
    if (i < n4) {
        float4 v = out[i];
        v.x *= inv; v.y *= inv; v.z *= inv; v.w *= inv;
        out[i] = v;
    }
}

extern "C" void kernel_launch(void* const* d_in, const int* in_sizes, int n_in,
                              void* d_out, int out_size, void* d_ws, size_t ws_size,
                              hipStream_t stream) {
    const float* contour = (const float*)d_in[0];
    float* out  = (float*)d_out;
    float* bmax = (float*)d_ws;

    const int bn = in_sizes[0] / (KV * 2);            // 8
    const int npix = bn * MAP_SIZE * MAP_SIZE;        // 524288 == out_size

    const int blocksPerImg = (MAP_SIZE * MAP_SIZE) / (64 * PPT);  // 256
    const int nb = bn * blocksPerImg;                              // 2048
    cdm_pass1<<<nb, 64, 0, stream>>>(contour, out, bmax);

    const int n4 = npix / 4;
    cdm_pass2<<<(n4 + 255) / 256, 256, 0, stream>>>((float4*)out, bmax, nb, n4);
}

// Round 14
// 22.160 us; speedup vs baseline: 1.3474x; 1.0717x over previous
//
#include <hip/hip_runtime.h>
#include <math.h>

#define MAP_SIZE 256
#define KV 64
#define HPX (1.0f / 256.0f)
#define TK 288539.0083f            // 2 * 100000 * log2(e)

__global__ __launch_bounds__(256) void cdm_pass1(
    const float* __restrict__ contour,   // (bn, KV, 2)
    float* __restrict__ out,             // (bn, 256, 256) unnormalized prod
    float* __restrict__ bmax)            // per-block max (no atomics)
{
    __shared__ __align__(16) float2 cv2[KV + 2];   // [64] = v0 wrap copy
    const int blocksPerImg = (MAP_SIZE * MAP_SIZE) / 256;  // 256
    const int bn  = blockIdx.x / blocksPerImg;
    const int pix = (blockIdx.x % blocksPerImg) * 256 + threadIdx.x;

    const float2* gsrc = (const float2*)contour + bn * KV;
    if (threadIdx.x < KV) cv2[threadIdx.x] = gsrc[threadIdx.x];
    if (threadIdx.x == 0) cv2[KV] = gsrc[0];
    __syncthreads();

    const float mx = (float)(pix >> 8) * HPX;
    const float my = (float)(pix & 255) * HPX;

    const float4 q0 = ((const float4*)cv2)[0];   // v0, v1
    float ax = q0.x - mx;                // carried A - m
    float ay = q0.y - my;
    float u  = __builtin_copysignf(1.0f, ay);

    float mindd = 1e30f;
    float wn4   = 0.0f;                  // 4x winding number (exact small ints)
    float scr   = 1e30f;                 // signed cr with min |cr|
    float sidx  = 0.0f;                  // its edge index (as float)

    // 16-op zero-trans edge step (PPT=1, max occupancy):
    //  dist: rx ry mul fmaf fmin | cr: mul fmaf | winding: un c dl s t fmaf
    //  argmin: cmp sel sel
    auto edge = [&](float bx, float by, float k) {
        const float rx = bx - mx;
        const float ry = by - my;
        const float rr = fmaf(ry, ry, rx * rx);
        mindd = fminf(mindd, rr);
        const float cr = fmaf(ay, rx, -(ax * ry));
        const float un = __builtin_copysignf(1.0f, ry);
        const float c  = __builtin_copysignf(1.0f, cr);
        const float dl = un - u;                      // {0, +-2}
        const float s  = c * dl;
        const float t  = fminf(s, 0.0f);
        wn4 = fmaf(t, -dl, wn4);                      // +-4 per crossing
        const bool better = __builtin_fabsf(cr) < __builtin_fabsf(scr);
        scr  = better ? cr : scr;
        sidx = better ? k  : sidx;
        ax = rx; ay = ry; u = un;
    };

    edge(q0.z, q0.w, 0.0f);                    // edge 0: v0 -> v1
    #pragma unroll 4
    for (int jj = 1; jj < KV / 2; ++jj) {
        const float4 t = ((const float4*)cv2)[jj];
        edge(t.x, t.y, (float)(2 * jj - 1));   // edge 2jj-1: B = v(2jj)
        edge(t.z, t.w, (float)(2 * jj));       // edge 2jj  : B = v(2jj+1)
    }
    edge(q0.x, q0.y, (float)(KV - 1));         // edge 63: v63 -> v0

    // epilogue: recompute dot for the argmin edge, one trans chain
    const int si = (int)sidx;
    const float2 A = cv2[si];
    const float2 B = cv2[si + 1];
    const float dax = A.x - mx, day = A.y - my;
    const float rbx = B.x - mx, rby = B.y - my;
    const float dot = fmaf(dax, rbx, day * rby);
    const float e   = __builtin_amdgcn_exp2f(__builtin_fabsf(scr) * TK);
    const float d2  = __builtin_amdgcn_rcpf(e + 1.0f);
    const float w   = fmaf(-0.5f, __builtin_copysignf(1.0f, dot), 0.5f); // [dot<0]
    const float corr = __builtin_copysignf(1.0f, scr) * d2 * w;

    const float resize = __builtin_fabsf(fmaf(wn4, 0.25f, corr));
    const float pv = resize * __builtin_amdgcn_sqrtf(mindd);
    out[bn * (MAP_SIZE * MAP_SIZE) + pix] = pv;

    // block max -> plain store (no global atomic)
    float m = pv;
    #pragma unroll
    for (int off = 32; off > 0; off >>= 1)
        m = fmaxf(m, __shfl_xor(m, off));

    __shared__ float wmax[4];
    const int lane = threadIdx.x & 63;
    const int wid  = threadIdx.x >> 6;
    if (lane == 0) wmax[wid] = m;
    __syncthreads();
    if (threadIdx.x == 0)
        bmax[blockIdx.x] = fmaxf(fmaxf(wmax[0], wmax[1]), fmaxf(wmax[2], wmax[3]));
}

__global__ __launch_bounds__(256) void cdm_pass2(
    float4* __restrict__ out, const float* __restrict__ bmax, int nb, int n4)
{
    // every block re-reduces the block-max array (8 KB, L2-resident)
    float m = 0.0f;
    for (int i = threadIdx.x; i < nb; i += 256) m = fmaxf(m, bmax[i]);
    #pragma unroll
    for (int off = 32; off > 0; off >>= 1)
        m = fmaxf(m, __shfl_xor(m, off));

    __shared__ float wm[4];
    if ((threadIdx.x & 63) == 0) wm[threadIdx.x >> 6] = m;
    __syncthreads();
    const float gm  = fmaxf(fmaxf(wm[0], wm[1]), fmaxf(wm[2], wm[3]));
    const float inv = 1.0f / gm;

    const int i = blockIdx.x * 256 + threadIdx.x;
    if (i < n4) {
        float4 v = out[i];
        v.x *= inv; v.y *= inv; v.z *= inv; v.w *= inv;
        out[i] = v;
    }
}

extern "C" void kernel_launch(void* const* d_in, const int* in_sizes, int n_in,
                              void* d_out, int out_size, void* d_ws, size_t ws_size,
                              hipStream_t stream) {
    const float* contour = (const float*)d_in[0];
    float* out  = (float*)d_out;
    float* bmax = (float*)d_ws;

    const int bn = in_sizes[0] / (KV * 2);            // 8
    const int npix = bn * MAP_SIZE * MAP_SIZE;        // 524288 == out_size

    const int blocksPerImg = (MAP_SIZE * MAP_SIZE) / 256;  // 256
    const int nb = bn * blocksPerImg;                       // 2048
    cdm_pass1<<<nb, 256, 0, stream>>>(contour, out, bmax);

    const int n4 = npix / 4;
    cdm_pass2<<<(n4 + 255) / 256, 256, 0, stream>>>((float4*)out, bmax, nb, n4);
}

// Round 15
// 19.233 us; speedup vs baseline: 1.5524x; 1.1522x over previous
//
#include <hip/hip_runtime.h>
#include <math.h>

#define MAP_SIZE 256
#define KV 64
#define HPX (1.0f / 256.0f)
#define TK 288539.0083f            // 2 * 100000 * log2(e)

__global__ __launch_bounds__(256) void cdm_pass1(
    const float* __restrict__ contour,   // (bn, KV, 2)
    float* __restrict__ out,             // (bn, 256, 256) unnormalized prod
    float* __restrict__ bmax)            // per-block max (no atomics)
{
    __shared__ __align__(16) float4 ec[KV];        // per-edge {C0, C1, A, By}
    __shared__ __align__(8)  float2 cv2[KV + 1];   // vertices + wrap
    const int blocksPerImg = 256;                  // one x-column per block
    const int bn  = blockIdx.x / blocksPerImg;
    const int col = blockIdx.x % blocksPerImg;
    const float mx = (float)col * HPX;             // wave-uniform

    // per-block precompute: column-expanded edge constants
    //   cr(my)   = C0 - my*C1,  C0 = AyBx - AxBy - mx*(Ay-By), C1 = Bx-Ax
    //   dist2(my)= A - 2By*my + my^2,  A = (Bx-mx)^2 + By^2
    const float2* gsrc = (const float2*)contour + bn * KV;
    if (threadIdx.x < KV) {
        const float2 Av = gsrc[threadIdx.x];
        const float2 Bv = gsrc[(threadIdx.x + 1) & (KV - 1)];
        cv2[threadIdx.x] = Av;
        if (threadIdx.x == 0) cv2[KV] = Av;        // v0 wrap
        const float C1 = Bv.x - Av.x;
        const float C0 = fmaf(Av.y, Bv.x, -(Av.x * Bv.y)) - mx * (Av.y - Bv.y);
        const float bx = Bv.x - mx;
        const float A  = fmaf(bx, bx, Bv.y * Bv.y);
        ec[threadIdx.x] = make_float4(C0, C1, A, Bv.y);
    }
    __syncthreads();

    const float my  = (float)threadIdx.x * HPX;
    const float m2y = -2.0f * my;

    float u = __builtin_copysignf(1.0f, cv2[0].y - my);

    float minp = 1e30f;                // min over edges of (A - 2By*my)
    float wn4  = 0.0f;                 // 4x winding number
    unsigned int kmin = 0xFFFFFFFFu;   // packed (|cr|, edge) argmin key

    // 12-op edge body; cr/rr chains fully independent (only u is carried)
    #pragma unroll 8
    for (int e = 0; e < KV; ++e) {
        const float4 f = ec[e];
        const float cr = fmaf(-my, f.y, f.x);
        const float rr = fmaf(m2y, f.w, f.z);
        minp = fminf(minp, rr);
        const float ry = f.w - my;
        const float un = __builtin_copysignf(1.0f, ry);
        const float c  = __builtin_copysignf(1.0f, cr);
        const float dl = un - u;                   // {0, +-2}
        const float s  = c * dl;
        const float t  = fminf(s, 0.0f);
        wn4 = fmaf(t, -dl, wn4);                   // +-4 per crossing
        const unsigned int key =
            (__float_as_uint(cr) & 0x7FFFFFC0u) | (unsigned int)e;  // v_and_or
        kmin = min(kmin, key);
        u = un;
    }

    // epilogue: reconstruct argmin edge's cr sign + dot, one trans chain
    const int si = (int)(kmin & 63u);
    const float4 fs = ec[si];
    const float crm = fmaf(-my, fs.y, fs.x);
    const float2 A = cv2[si];
    const float2 B = cv2[si + 1];
    const float dax = A.x - mx, day = A.y - my;
    const float rbx = B.x - mx, rby = B.y - my;
    const float dot = fmaf(dax, rbx, day * rby);
    const float ee  = __builtin_amdgcn_exp2f(__builtin_fabsf(crm) * TK);
    const float d2  = __builtin_amdgcn_rcpf(ee + 1.0f);
    const float w   = fmaf(-0.5f, __builtin_copysignf(1.0f, dot), 0.5f); // [dot<0]
    const float corr = __builtin_copysignf(1.0f, crm) * d2 * w;

    const float resize = __builtin_fabsf(fmaf(wn4, 0.25f, corr));
    const float mindd  = fmaxf(fmaf(my, my, minp), 0.0f);  // + my^2, guard
    const float pv = resize * __builtin_amdgcn_sqrtf(mindd);
    out[bn * (MAP_SIZE * MAP_SIZE) + (col << 8) + threadIdx.x] = pv;

    // block max -> plain store (no global atomic)
    float m = pv;
    #pragma unroll
    for (int off = 32; off > 0; off >>= 1)
        m = fmaxf(m, __shfl_xor(m, off));

    __shared__ float wmax[4];
    const int lane = threadIdx.x & 63;
    const int wid  = threadIdx.x >> 6;
    if (lane == 0) wmax[wid] = m;
    __syncthreads();
    if (threadIdx.x == 0)
        bmax[blockIdx.x] = fmaxf(fmaxf(wmax[0], wmax[1]), fmaxf(wmax[2], wmax[3]));
}

__global__ __launch_bounds__(256) void cdm_pass2(
    float4* __restrict__ out, const float* __restrict__ bmax, int nb, int n4)
{
    // every block re-reduces the block-max array (8 KB, L2-resident)
    float m = 0.0f;
    for (int i = threadIdx.x; i < nb; i += 256) m = fmaxf(m, bmax[i]);
    #pragma unroll
    for (int off = 32; off > 0; off >>= 1)
        m = fmaxf(m, __shfl_xor(m, off));

    __shared__ float wm[4];
    if ((threadIdx.x & 63) == 0) wm[threadIdx.x >> 6] = m;
    __syncthreads();
    const float gm  = fmaxf(fmaxf(wm[0], wm[1]), fmaxf(wm[2], wm[3]));
    const float inv = 1.0f / gm;

    const int i = blockIdx.x * 256 + threadIdx.x;
    if (i < n4) {
        float4 v = out[i];
        v.x *= inv; v.y *= inv; v.z *= inv; v.w *= inv;
        out[i] = v;
    }
}

extern "C" void kernel_launch(void* const* d_in, const int* in_sizes, int n_in,
                              void* d_out, int out_size, void* d_ws, size_t ws_size,
                              hipStream_t stream) {
    const float* contour = (const float*)d_in[0];
    float* out  = (float*)d_out;
    float* bmax = (float*)d_ws;

    const int bn = in_sizes[0] / (KV * 2);            // 8
    const int npix = bn * MAP_SIZE * MAP_SIZE;        // 524288 == out_size

    const int nb = bn * 256;                          // 2048
    cdm_pass1<<<nb, 256, 0, stream>>>(contour, out, bmax);

    const int n4 = npix / 4;
    cdm_pass2<<<(n4 + 255) / 256, 256, 0, stream>>>((float4*)out, bmax, nb, n4);
}

// Round 16
// 18.992 us; speedup vs baseline: 1.5721x; 1.0127x over previous
//
#include <hip/hip_runtime.h>
#include <math.h>

#define MAP_SIZE 256
#define KV 64
#define HPX (1.0f / 256.0f)
#define TK 288539.0083f            // 2 * 100000 * log2(e)

__global__ __launch_bounds__(256) void cdm_pass1(
    const float* __restrict__ contour,   // (bn, KV, 2)
    float* __restrict__ out,             // (bn, 256, 256) unnormalized prod
    float* __restrict__ bmax)            // per-block max (no atomics)
{
    // 8B per edge: {dx_k = Vx_k - mx (uniform), Vy_k}; [64] = v0 wrap
    __shared__ __align__(8) float2 ev[KV + 1];
    const int blocksPerImg = 256;                  // one x-column per block
    const int bn  = blockIdx.x / blocksPerImg;
    const int col = blockIdx.x % blocksPerImg;
    const float mx = (float)col * HPX;             // wave-uniform

    const float2* gsrc = (const float2*)contour + bn * KV;
    if (threadIdx.x < KV) {
        const float2 v = gsrc[threadIdx.x];
        ev[threadIdx.x] = make_float2(v.x - mx, v.y);
        if (threadIdx.x == 0) ev[KV] = make_float2(v.x - mx, v.y);
    }
    __syncthreads();

    const float my = (float)threadIdx.x * HPX;

    const float2 e0 = ev[0];
    float ax = e0.x;                     // carried A-m (x part uniform)
    float ay = e0.y - my;
    float u  = __builtin_copysignf(1.0f, ay);

    float mindd = 1e30f;
    float wn4   = 0.0f;                  // 4x winding number (exact small ints)
    unsigned int kmin = 0xFFFFFFFFu;     // packed (|cr|, edge) argmin key

    // ~14-op edge body, 8B broadcast ds_read_b64 per edge
    #pragma unroll
    for (int k = 0; k < KV; ++k) {
        const float2 w = ev[k + 1];                  // {dxB, VyB}
        const float ry = w.y - my;
        const float cr = fmaf(ay, w.x, -(ax * ry));
        const float rr = fmaf(ry, ry, w.x * w.x);
        mindd = fminf(mindd, rr);
        const float un = __builtin_copysignf(1.0f, ry);
        const float c  = __builtin_copysignf(1.0f, cr);
        const float dl = un - u;                     // {0, +-2}
        const float s  = c * dl;
        const float t  = fminf(s, 0.0f);
        wn4 = fmaf(t, -dl, wn4);                     // +-4 per crossing
        const unsigned int key =
            (__float_as_uint(cr) & 0x7FFFFFC0u) | (unsigned int)k;
        kmin = min(kmin, key);
        ax = w.x; ay = ry; u = un;
    }

    // epilogue: reconstruct argmin edge's cr + dot from ev, one trans chain
    const int si = (int)(kmin & 63u);
    const float2 A = ev[si];
    const float2 B = ev[si + 1];
    const float day = A.y - my;
    const float rby = B.y - my;
    const float crm = fmaf(day, B.x, -(A.x * rby));
    const float dot = fmaf(A.x, B.x, day * rby);
    const float ee  = __builtin_amdgcn_exp2f(__builtin_fabsf(crm) * TK);
    const float d2  = __builtin_amdgcn_rcpf(ee + 1.0f);
    const float w   = fmaf(-0.5f, __builtin_copysignf(1.0f, dot), 0.5f); // [dot<0]
    const float corr = __builtin_copysignf(1.0f, crm) * d2 * w;

    const float resize = __builtin_fabsf(fmaf(wn4, 0.25f, corr));
    const float pv = resize * __builtin_amdgcn_sqrtf(mindd);
    out[bn * (MAP_SIZE * MAP_SIZE) + (col << 8) + threadIdx.x] = pv;

    // block max -> plain store (no global atomic)
    float m = pv;
    #pragma unroll
    for (int off = 32; off > 0; off >>= 1)
        m = fmaxf(m, __shfl_xor(m, off));

    __shared__ float wmax[4];
    const int lane = threadIdx.x & 63;
    const int wid  = threadIdx.x >> 6;
    if (lane == 0) wmax[wid] = m;
    __syncthreads();
    if (threadIdx.x == 0)
        bmax[blockIdx.x] = fmaxf(fmaxf(wmax[0], wmax[1]), fmaxf(wmax[2], wmax[3]));
}

__global__ __launch_bounds__(256) void cdm_pass2(
    float4* __restrict__ out, const float* __restrict__ bmax, int nb, int n4)
{
    // every block re-reduces the block-max array (8 KB, L2-resident)
    float m = 0.0f;
    for (int i = threadIdx.x; i < nb; i += 256) m = fmaxf(m, bmax[i]);
    #pragma unroll
    for (int off = 32; off > 0; off >>= 1)
        m = fmaxf(m, __shfl_xor(m, off));

    __shared__ float wm[4];
    if ((threadIdx.x & 63) == 0) wm[threadIdx.x >> 6] = m;
    __syncthreads();
    const float gm  = fmaxf(fmaxf(wm[0], wm[1]), fmaxf(wm[2], wm[3]));
    const float inv = 1.0f / gm;

    const int i = blockIdx.x * 256 + threadIdx.x;
    if (i < n4) {
        float4 v = out[i];
        v.x *= inv; v.y *= inv; v.z *= inv; v.w *= inv;
        out[i] = v;
    }
}

extern "C" void kernel_launch(void* const* d_in, const int* in_sizes, int n_in,
                              void* d_out, int out_size, void* d_ws, size_t ws_size,
                              hipStream_t stream) {
    const float* contour = (const float*)d_in[0];
    float* out  = (float*)d_out;
    float* bmax = (float*)d_ws;

    const int bn = in_sizes[0] / (KV * 2);            // 8
    const int npix = bn * MAP_SIZE * MAP_SIZE;        // 524288 == out_size

    const int nb = bn * 256;                          // 2048
    cdm_pass1<<<nb, 256, 0, stream>>>(contour, out, bmax);

    const int n4 = npix / 4;
    cdm_pass2<<<(n4 + 255) / 256, 256, 0, stream>>>((float4*)out, bmax, nb, n4);
}

// Round 17
// 16.814 us; speedup vs baseline: 1.7758x; 1.1295x over previous
//
#include <hip/hip_runtime.h>
#include <math.h>

#define MS 256
#define KV 64
#define HPX (1.0f / 256.0f)
#define TK 288539.0083f            // 2 * 100000 * log2(e)
#define TAUE 1.2e-4f               // |cr| beyond this: d2 = 1/(exp(2K|cr|)+1) < 2^-34

__global__ __launch_bounds__(256) void cdm_pass1(
    const float* __restrict__ contour,   // (bn, KV, 2)
    float* __restrict__ out,             // (bn, 256, 256) unnormalized prod
    float* __restrict__ bmax)            // per-block max (no atomics)
{
    __shared__ __align__(16) float2 vlds[KV + 2];  // vertices + wrap
    __shared__ int   evt[2][MS + 1];               // winding interval endpoints
    __shared__ float corr[2][MS];                  // tanh-deviation scatter
    __shared__ int   part[2][4];
    __shared__ float wmax[4];

    const int bn = blockIdx.x >> 7;          // image (128 column-pairs each)
    const int cp = blockIdx.x & 127;
    const float mx0 = (float)(2 * cp) * HPX;
    const float mx1 = mx0 + HPX;
    const int tid = threadIdx.x;

    for (int i = tid; i < 2 * (MS + 1); i += 256) ((int*)evt)[i] = 0;
    for (int i = tid; i < 2 * MS; i += 256) ((float*)corr)[i] = 0.0f;

    const float2* gsrc = (const float2*)contour + bn * KV;
    if (tid < KV) vlds[tid] = gsrc[tid];
    if (tid == 0) vlds[KV] = gsrc[0];
    __syncthreads();

    // ---- scatter: 128 tasks = 64 edges x 2 columns ----
    if (tid < 128) {
        const int e = tid & 63;
        const int c = tid >> 6;
        const float mx = c ? mx1 : mx0;
        const float2 A = vlds[e];
        const float2 B = vlds[e + 1];
        const float C1 = B.x - A.x;                     // cr(my) = C0 - my*C1
        const float C0 = fmaf(A.y, B.x, -(A.x * B.y)) + mx * (B.y - A.y);
        const bool  up = B.y > A.y;
        const float lo = fminf(A.y, B.y);
        const float hi = fmaxf(A.y, B.y);
        const float y0 = C0 * __builtin_amdgcn_rcpf(C1);   // may be +-inf/NaN

        // winding interval: up needs cr<0, down needs cr>=0
        const bool cut_low = (up == (C1 > 0.0f));
        const float l = cut_low ? fmaxf(lo, y0) : lo;
        const float h = cut_low ? hi : fminf(hi, y0);
        if (l < h) {
            const int jl = (int)ceilf(fminf(fmaxf(l * 256.0f, 0.0f), 256.0f));
            const int jh = (int)ceilf(fminf(fmaxf(h * 256.0f, 0.0f), 256.0f));
            if (jl < jh) {
                const int dir = up ? 1 : -1;
                atomicAdd(&evt[c][jl], dir);
                atomicAdd(&evt[c][jh], -dir);
            }
        }

        // corr scatter: rows with |cr| < TAUE, exact dot<0 gate
        const float aC1 = __builtin_fabsf(C1);
        float wf = TAUE * __builtin_amdgcn_rcpf(aC1) * 256.0f;  // band half-width in rows
        const bool full = !(wf < 300.0f);                       // near-vertical: scan span
        const float y0c = fminf(fmaxf(y0, -4.0f), 4.0f);        // NaN -> -4 (full path anyway)
        const int W  = (int)fminf(wf, 300.0f) + 1;
        const int jc = (int)(y0c * 256.0f);
        const int sl = (int)ceilf(lo * 256.0f) - 1;
        const int sh = (int)(hi * 256.0f) + 1;
        int j0 = full ? max(sl, 0) : max(max(jc - W, sl), 0);
        int j1 = full ? min(sh, 255) : min(min(jc + W, sh), 255);
        for (int j = j0; j <= j1; ++j) {
            const float my = (float)j * HPX;
            const float cr = fmaf(-my, C1, C0);
            const float acr = __builtin_fabsf(cr);
            if (acr < TAUE) {
                const float dot = fmaf(A.x - mx, B.x - mx, (A.y - my) * (B.y - my));
                if (dot < 0.0f) {
                    const float e2 = __builtin_amdgcn_exp2f(acr * TK);
                    const float d2 = __builtin_amdgcn_rcpf(e2 + 1.0f);
                    atomicAdd(&corr[c][j], __builtin_copysignf(d2, cr));
                }
            }
        }
    }
    __syncthreads();

    // ---- per-column inclusive prefix scan of evt -> exact winding ----
    int v0 = evt[0][tid];
    int v1 = evt[1][tid];
    const int lane = tid & 63;
    const int wv = tid >> 6;
    #pragma unroll
    for (int off = 1; off < 64; off <<= 1) {
        const int t0 = __shfl_up(v0, off);
        const int t1 = __shfl_up(v1, off);
        if (lane >= off) { v0 += t0; v1 += t1; }
    }
    if (lane == 63) { part[0][wv] = v0; part[1][wv] = v1; }
    __syncthreads();
    #pragma unroll
    for (int w = 0; w < 3; ++w)
        if (wv > w) { v0 += part[0][w]; v1 += part[1][w]; }

    // ---- dense part: min distance to 64 vertices (2 ops/px/vertex) ----
    const float my = (float)tid * HPX;
    float md0 = 1e30f, md1 = 1e30f;
    const float4* vp = (const float4*)vlds;
    #pragma unroll 8
    for (int k = 0; k < KV / 2; ++k) {
        const float4 q = vp[k];
        float t, s;
        t = q.y - my; t = t * t;
        s = q.x - mx0; md0 = fminf(md0, fmaf(s, s, t));
        s = q.x - mx1; md1 = fminf(md1, fmaf(s, s, t));
        t = q.w - my; t = t * t;
        s = q.z - mx0; md0 = fminf(md0, fmaf(s, s, t));
        s = q.z - mx1; md1 = fminf(md1, fmaf(s, s, t));
    }

    const float r0 = __builtin_fabsf((float)v0 + corr[0][tid]);
    const float r1 = __builtin_fabsf((float)v1 + corr[1][tid]);
    const float pv0 = r0 * __builtin_amdgcn_sqrtf(md0);
    const float pv1 = r1 * __builtin_amdgcn_sqrtf(md1);

    float* ob = out + bn * (MS * MS) + (2 * cp) * MS;
    ob[tid] = pv0;
    ob[MS + tid] = pv1;

    // block max -> plain store (no global atomic)
    float m = fmaxf(pv0, pv1);
    #pragma unroll
    for (int off = 32; off > 0; off >>= 1)
        m = fmaxf(m, __shfl_xor(m, off));
    if (lane == 0) wmax[wv] = m;
    __syncthreads();
    if (tid == 0)
        bmax[blockIdx.x] = fmaxf(fmaxf(wmax[0], wmax[1]), fmaxf(wmax[2], wmax[3]));
}

__global__ __launch_bounds__(256) void cdm_pass2(
    float4* __restrict__ out, const float* __restrict__ bmax, int nb, int n4)
{
    float m = 0.0f;
    for (int i = threadIdx.x; i < nb; i += 256) m = fmaxf(m, bmax[i]);
    #pragma unroll
    for (int off = 32; off > 0; off >>= 1)
        m = fmaxf(m, __shfl_xor(m, off));

    __shared__ float wm[4];
    if ((threadIdx.x & 63) == 0) wm[threadIdx.x >> 6] = m;
    __syncthreads();
    const float gm  = fmaxf(fmaxf(wm[0], wm[1]), fmaxf(wm[2], wm[3]));
    const float inv = 1.0f / gm;

    const int i = blockIdx.x * 256 + threadIdx.x;
    if (i < n4) {
        float4 v = out[i];
        v.x *= inv; v.y *= inv; v.z *= inv; v.w *= inv;
        out[i] = v;
    }
}

extern "C" void kernel_launch(void* const* d_in, const int* in_sizes, int n_in,
                              void* d_out, int out_size, void* d_ws, size_t ws_size,
                              hipStream_t stream) {
    const float* contour = (const float*)d_in[0];
    float* out  = (float*)d_out;
    float* bmax = (float*)d_ws;

    const int bn = in_sizes[0] / (KV * 2);            // 8
    const int npix = bn * MS * MS;                    // 524288 == out_size

    const int nb = bn * 128;                          // 1024 (2 columns/block)
    cdm_pass1<<<nb, 256, 0, stream>>>(contour, out, bmax);

    const int n4 = npix / 4;
    cdm_pass2<<<(n4 + 255) / 256, 256, 0, stream>>>((float4*)out, bmax, nb, n4);
}

// Round 18
// 16.176 us; speedup vs baseline: 1.8458x; 1.0395x over previous
//
#include <hip/hip_runtime.h>
#include <math.h>

#define MS 256
#define KV 64
#define HPX (1.0f / 256.0f)
#define TK 288539.0083f            // 2 * 100000 * log2(e)
#define TAUE 1.2e-4f               // |cr| beyond this: d2 < 2^-34

__global__ __launch_bounds__(256) void cdm_pass1(
    const float* __restrict__ contour,   // (bn, KV, 2)
    float* __restrict__ out,             // (bn, 256, 256) unnormalized prod
    float* __restrict__ bmax)            // per-block max (no atomics)
{
    __shared__ __align__(16) float2 vlds[KV + 2];  // vertices + wrap
    __shared__ int   evt[4][MS + 1];               // winding interval endpoints
    __shared__ float corr[4][MS];                  // tanh-deviation scatter
    __shared__ int   part[4][4];
    __shared__ float wmax[4];

    const int bn = blockIdx.x >> 6;          // image (64 column-quads each)
    const int cq = blockIdx.x & 63;
    const float mx0 = (float)(4 * cq) * HPX;
    const float mx1 = mx0 + HPX;
    const float mx2 = mx0 + 2.0f * HPX;
    const float mx3 = mx0 + 3.0f * HPX;
    const int tid = threadIdx.x;

    for (int i = tid; i < 4 * (MS + 1); i += 256) ((int*)evt)[i] = 0;
    for (int i = tid; i < 4 * MS; i += 256) ((float*)corr)[i] = 0.0f;

    const float2* gsrc = (const float2*)contour + bn * KV;
    if (tid < KV) vlds[tid] = gsrc[tid];
    if (tid == 0) vlds[KV] = gsrc[0];
    __syncthreads();

    // ---- scatter: 256 tasks = 64 edges x 4 columns ----
    {
        const int e = tid & 63;
        const int c = tid >> 6;
        const float mx = mx0 + (float)c * HPX;
        const float2 A = vlds[e];
        const float2 B = vlds[e + 1];
        const float C1 = B.x - A.x;                     // cr(my) = C0 - my*C1
        const float C0 = fmaf(A.y, B.x, -(A.x * B.y)) + mx * (B.y - A.y);
        const bool  up = B.y > A.y;
        const float lo = fminf(A.y, B.y);
        const float hi = fmaxf(A.y, B.y);
        const float y0 = C0 * __builtin_amdgcn_rcpf(C1);   // may be +-inf/NaN

        // winding interval: up needs cr<0, down needs cr>=0
        const bool cut_low = (up == (C1 > 0.0f));
        const float l = cut_low ? fmaxf(lo, y0) : lo;
        const float h = cut_low ? hi : fminf(hi, y0);
        if (l < h) {
            const int jl = (int)ceilf(fminf(fmaxf(l * 256.0f, 0.0f), 256.0f));
            const int jh = (int)ceilf(fminf(fmaxf(h * 256.0f, 0.0f), 256.0f));
            if (jl < jh) {
                const int dir = up ? 1 : -1;
                atomicAdd(&evt[c][jl], dir);
                atomicAdd(&evt[c][jh], -dir);
            }
        }

        // corr scatter: rows with |cr| < TAUE, exact dot<0 gate
        const float aC1 = __builtin_fabsf(C1);
        float wf = TAUE * __builtin_amdgcn_rcpf(aC1) * 256.0f;  // half-width in rows
        const bool full = !(wf < 300.0f);                       // near-vertical
        const float y0c = fminf(fmaxf(y0, -4.0f), 4.0f);        // NaN-safe
        const int W  = (int)fminf(wf, 300.0f) + 1;
        const int jc = (int)(y0c * 256.0f);
        const int sl = (int)ceilf(lo * 256.0f) - 1;
        const int sh = (int)(hi * 256.0f) + 1;
        int j0 = full ? max(sl, 0) : max(max(jc - W, sl), 0);
        int j1 = full ? min(sh, 255) : min(min(jc + W, sh), 255);
        for (int j = j0; j <= j1; ++j) {
            const float my = (float)j * HPX;
            const float cr = fmaf(-my, C1, C0);
            const float acr = __builtin_fabsf(cr);
            if (acr < TAUE) {
                const float dot = fmaf(A.x - mx, B.x - mx, (A.y - my) * (B.y - my));
                if (dot < 0.0f) {
                    const float e2 = __builtin_amdgcn_exp2f(acr * TK);
                    const float d2 = __builtin_amdgcn_rcpf(e2 + 1.0f);
                    atomicAdd(&corr[c][j], __builtin_copysignf(d2, cr));
                }
            }
        }
    }
    __syncthreads();

    // ---- per-column inclusive prefix scan of evt -> exact winding ----
    int v0 = evt[0][tid];
    int v1 = evt[1][tid];
    int v2 = evt[2][tid];
    int v3 = evt[3][tid];
    const int lane = tid & 63;
    const int wv = tid >> 6;
    #pragma unroll
    for (int off = 1; off < 64; off <<= 1) {
        const int t0 = __shfl_up(v0, off);
        const int t1 = __shfl_up(v1, off);
        const int t2 = __shfl_up(v2, off);
        const int t3 = __shfl_up(v3, off);
        if (lane >= off) { v0 += t0; v1 += t1; v2 += t2; v3 += t3; }
    }
    if (lane == 63) { part[0][wv] = v0; part[1][wv] = v1;
                      part[2][wv] = v2; part[3][wv] = v3; }
    __syncthreads();
    #pragma unroll
    for (int w = 0; w < 3; ++w)
        if (wv > w) { v0 += part[0][w]; v1 += part[1][w];
                      v2 += part[2][w]; v3 += part[3][w]; }

    // ---- dense part: min distance to 64 vertices, 4 columns share (Vy-my)^2 ----
    const float my = (float)tid * HPX;
    float md0 = 1e30f, md1 = 1e30f, md2 = 1e30f, md3 = 1e30f;
    const float4* vp = (const float4*)vlds;
    #pragma unroll 8
    for (int k = 0; k < KV / 2; ++k) {
        const float4 q = vp[k];
        float t, s;
        t = q.y - my; t = t * t;
        s = q.x - mx0; md0 = fminf(md0, fmaf(s, s, t));
        s = q.x - mx1; md1 = fminf(md1, fmaf(s, s, t));
        s = q.x - mx2; md2 = fminf(md2, fmaf(s, s, t));
        s = q.x - mx3; md3 = fminf(md3, fmaf(s, s, t));
        t = q.w - my; t = t * t;
        s = q.z - mx0; md0 = fminf(md0, fmaf(s, s, t));
        s = q.z - mx1; md1 = fminf(md1, fmaf(s, s, t));
        s = q.z - mx2; md2 = fminf(md2, fmaf(s, s, t));
        s = q.z - mx3; md3 = fminf(md3, fmaf(s, s, t));
    }

    const float r0 = __builtin_fabsf((float)v0 + corr[0][tid]);
    const float r1 = __builtin_fabsf((float)v1 + corr[1][tid]);
    const float r2 = __builtin_fabsf((float)v2 + corr[2][tid]);
    const float r3 = __builtin_fabsf((float)v3 + corr[3][tid]);
    const float pv0 = r0 * __builtin_amdgcn_sqrtf(md0);
    const float pv1 = r1 * __builtin_amdgcn_sqrtf(md1);
    const float pv2 = r2 * __builtin_amdgcn_sqrtf(md2);
    const float pv3 = r3 * __builtin_amdgcn_sqrtf(md3);

    float* ob = out + bn * (MS * MS) + (4 * cq) * MS;
    ob[tid] = pv0;
    ob[MS + tid] = pv1;
    ob[2 * MS + tid] = pv2;
    ob[3 * MS + tid] = pv3;

    // block max -> plain store (no global atomic)
    float m = fmaxf(fmaxf(pv0, pv1), fmaxf(pv2, pv3));
    #pragma unroll
    for (int off = 32; off > 0; off >>= 1)
        m = fmaxf(m, __shfl_xor(m, off));
    if (lane == 0) wmax[wv] = m;
    __syncthreads();
    if (tid == 0)
        bmax[blockIdx.x] = fmaxf(fmaxf(wmax[0], wmax[1]), fmaxf(wmax[2], wmax[3]));
}

__global__ __launch_bounds__(256) void cdm_pass2(
    float4* __restrict__ out, const float* __restrict__ bmax, int nb, int n4)
{
    float m = 0.0f;
    for (int i = threadIdx.x; i < nb; i += 256) m = fmaxf(m, bmax[i]);
    #pragma unroll
    for (int off = 32; off > 0; off >>= 1)
        m = fmaxf(m, __shfl_xor(m, off));

    __shared__ float wm[4];
    if ((threadIdx.x & 63) == 0) wm[threadIdx.x >> 6] = m;
    __syncthreads();
    const float gm  = fmaxf(fmaxf(wm[0], wm[1]), fmaxf(wm[2], wm[3]));
    const float inv = 1.0f / gm;

    const int i = blockIdx.x * 256 + threadIdx.x;
    if (i < n4) {
        float4 v = out[i];
        v.x *= inv; v.y *= inv; v.z *= inv; v.w *= inv;
        out[i] = v;
    }
}

extern "C" void kernel_launch(void* const* d_in, const int* in_sizes, int n_in,
                              void* d_out, int out_size, void* d_ws, size_t ws_size,
                              hipStream_t stream) {
    const float* contour = (const float*)d_in[0];
    float* out  = (float*)d_out;
    float* bmax = (float*)d_ws;

    const int bn = in_sizes[0] / (KV * 2);            // 8
    const int npix = bn * MS * MS;                    // 524288 == out_size

    const int nb = bn * 64;                           // 512 (4 columns/block)
    cdm_pass1<<<nb, 256, 0, stream>>>(contour, out, bmax);

    const int n4 = npix / 4;
    cdm_pass2<<<(n4 + 255) / 256, 256, 0, stream>>>((float4*)out, bmax, nb, n4);
}